// Round 2
// baseline (272.455 us; speedup 1.0000x reference)
//
#include <hip/hip_runtime.h>
#include <cmath>

// GCN 2-layer, dims 1 -> 16 -> 2, N=100K, E=6.4M.
//
// Model (R1..R13, counter-validated): scattered LDS atomics are the floor at
// ~4.2 cyc/atomic/CU; every 1-atomic/edge pass costs ~44us. R13 = 4 atomic
// passes (scatter, deg, aggf, agg2u64) = 228us.
// R14: cut to 2 atomic passes. Pass 2 (k_place) uses the histogram atomic's
// RETURN VALUE as a placement cursor into padded per-node slots (Poisson
// lambda~6.4 at C2=10, NPAD~lambda+2.5*sqrt; overflow -> exact spill list).
// Both aggregation passes then become atomic-free per-node serial sums
// (p-major slot layout -> lane-coalesced reads, 4 nodes/thread for ILP),
// and the u64 fixed-point hack for layer 2 disappears (plain float2).
// R15 = R14 resubmit (container infra failure, no verdict) + C2 8->10 for
// CU load balance on k_place (tail 1.3x -> 1.04x).

static constexpr int CSH   = 11;           // log2 bucket width
static constexpr int CW    = 1 << CSH;     // 2048 nodes / bucket
static constexpr int MAXNC = 64;           // n <= 131072
static constexpr int NB1   = 512;          // scatter blocks / segments
static constexpr int SPAD  = 4096;         // spill slots / region

__host__ __device__ __forceinline__ int chunk_of(int e) {
    return ((e + NB1 * 4 - 1) / (NB1 * 4)) * 4;   // 4-aligned per-block chunk
}

// ---- 1) scatter into padded block-local regions, local cursors ----
__global__ __launch_bounds__(256) void k_scatter(const int* __restrict__ row,
        const int* __restrict__ col, int* __restrict__ P1, int* __restrict__ CNT,
        int e, int NC, int PAD) {
    __shared__ int cur[MAXNC];
    const int b = blockIdx.x, tid = threadIdx.x;
    for (int j = tid; j < NC; j += 256) cur[j] = 0;
    __syncthreads();
    const int chunk = chunk_of(e);
    const int lo = b * chunk, end = min(lo + chunk, e);
    const size_t rbase = (size_t)b * NC * PAD;
    for (int i0 = lo + tid * 4; i0 + 3 < end; i0 += 1024) {
        int4 c4 = *reinterpret_cast<const int4*>(col + i0);
        int4 r4 = *reinterpret_cast<const int4*>(row + i0);
        int ca[4] = {c4.x, c4.y, c4.z, c4.w};
        int ra[4] = {r4.x, r4.y, r4.z, r4.w};
#pragma unroll
        for (int m = 0; m < 4; ++m) {
            int k = ca[m] >> CSH;
            int pos = atomicAdd(&cur[k], 1);
            if (pos < PAD)   // overflow guard (P ~1e-12 at PAD = mean+8sigma)
                P1[rbase + (size_t)k * PAD + pos] = (ra[m] << CSH) | (ca[m] & (CW - 1));
        }
    }
    const int tailStart = lo + ((end - lo) & ~3);
    for (int i = tailStart + tid; i < end; i += 256) {
        int c = col[i], r = row[i];
        int k = c >> CSH;
        int pos = atomicAdd(&cur[k], 1);
        if (pos < PAD)
            P1[rbase + (size_t)k * PAD + pos] = (r << CSH) | (c & (CW - 1));
    }
    __syncthreads();
    for (int j = tid; j < NC; j += 256) CNT[b * NC + j] = min(cur[j], PAD);
}

// ---- 2) R14 place: histogram atomic return value IS the slot cursor ----
// P2 layout per region r: p2[pos*CW + l] = row (p-major -> coalesced reads).
// CNT2[r*CW+l] = FULL count (deg partial). Overflow -> exact spill list.
__global__ __launch_bounds__(512) void k_place(const int* __restrict__ P1,
        const int* __restrict__ CNT, int* __restrict__ P2, int* __restrict__ CNT2,
        int* __restrict__ SP, int* __restrict__ SPC,
        int NC, int C, int PAD, int NPAD) {
    __shared__ int cur[CW];
    __shared__ int scur;
    const int k = blockIdx.x / C, j = blockIdx.x % C;
    const size_t r = blockIdx.x;
    const int tid = threadIdx.x, wave = tid >> 6, lane = tid & 63;
    for (int q = tid; q < CW; q += 512) cur[q] = 0;
    if (tid == 0) scur = 0;
    __syncthreads();
    int* __restrict__ p2 = P2 + r * CW * (size_t)NPAD;
    int* __restrict__ sp = SP + r * SPAD;
    const int b0 = (j * NB1) / C, b1 = ((j + 1) * NB1) / C;
    for (int b = b0 + wave; b < b1; b += 8) {
        const int cnt = CNT[b * NC + k];
        const int* seg = P1 + ((size_t)b * NC + k) * PAD;
        const int nv = cnt & ~3;
        for (int i = lane * 4; i < nv; i += 256) {
            int4 a = *reinterpret_cast<const int4*>(seg + i);
            int vv[4] = {a.x, a.y, a.z, a.w};
#pragma unroll
            for (int m = 0; m < 4; ++m) {
                const int v = vv[m];
                const int l = v & (CW - 1);
                const int pos = atomicAdd(&cur[l], 1);
                if (pos < NPAD) p2[(size_t)pos * CW + l] = v >> CSH;
                else { int s0 = atomicAdd(&scur, 1); if (s0 < SPAD) sp[s0] = v; }
            }
        }
        for (int i = nv + lane; i < cnt; i += 64) {
            const int v = seg[i];
            const int l = v & (CW - 1);
            const int pos = atomicAdd(&cur[l], 1);
            if (pos < NPAD) p2[(size_t)pos * CW + l] = v >> CSH;
            else { int s0 = atomicAdd(&scur, 1); if (s0 < SPAD) sp[s0] = v; }
        }
    }
    __syncthreads();
    for (int q = tid; q < CW; q += 512) CNT2[r * CW + q] = cur[q];
    if (tid == 0) SPC[r] = min(scur, SPAD);
}

// ---- 3) atomic-free gather-sum layer 1: S[l] = sum t[row] over slots ----
__global__ __launch_bounds__(512) void k_gath1(const int* __restrict__ P2,
        const int* __restrict__ CNT2, const int* __restrict__ SP,
        const int* __restrict__ SPC, const float* __restrict__ t,
        float* __restrict__ Pf, int NPAD) {
    __shared__ float sbin[CW];
    const size_t r = blockIdx.x;
    const int tid = threadIdx.x;
    for (int q = tid; q < CW; q += 512) sbin[q] = 0.0f;
    __syncthreads();
    const int spc = SPC[r];
    for (int i = tid; i < spc; i += 512) {        // rare overflow edges
        const int v = SP[r * SPAD + i];
        atomicAdd(&sbin[v & (CW - 1)], t[v >> CSH]);
    }
    __syncthreads();
    const int* __restrict__ p2 = P2 + r * CW * (size_t)NPAD;
    const int* __restrict__ cc = CNT2 + r * CW;
    const int l0 = tid, l1 = tid + 512, l2 = tid + 1024, l3 = tid + 1536;
    const int c0 = min(cc[l0], NPAD), c1 = min(cc[l1], NPAD);
    const int c2 = min(cc[l2], NPAD), c3 = min(cc[l3], NPAD);
    float S0 = sbin[l0], S1 = sbin[l1], S2 = sbin[l2], S3 = sbin[l3];
    const int cm = max(max(c0, c1), max(c2, c3));
    for (int p = 0; p < cm; ++p) {                 // 4 indep dep-chains/thread
        const int* rp = p2 + (size_t)p * CW;
        if (p < c0) S0 += t[rp[l0]];
        if (p < c1) S1 += t[rp[l1]];
        if (p < c2) S2 += t[rp[l2]];
        if (p < c3) S3 += t[rp[l3]];
    }
    float* o = Pf + r * CW;
    o[l0] = S0; o[l1] = S1; o[l2] = S2; o[l3] = S3;
}

// ---- 4) atomic-free gather-sum layer 2 (plain float2, no u64 hack) ----
__global__ __launch_bounds__(512) void k_gath2(const int* __restrict__ P2,
        const int* __restrict__ CNT2, const int* __restrict__ SP,
        const int* __restrict__ SPC, const float2* __restrict__ u,
        float2* __restrict__ Pf2, int NPAD) {
    __shared__ float sbx[CW];
    __shared__ float sby[CW];
    const size_t r = blockIdx.x;
    const int tid = threadIdx.x;
    for (int q = tid; q < CW; q += 512) { sbx[q] = 0.0f; sby[q] = 0.0f; }
    __syncthreads();
    const int spc = SPC[r];
    for (int i = tid; i < spc; i += 512) {
        const int v = SP[r * SPAD + i];
        float2 uv = u[v >> CSH];
        atomicAdd(&sbx[v & (CW - 1)], uv.x);
        atomicAdd(&sby[v & (CW - 1)], uv.y);
    }
    __syncthreads();
    const int* __restrict__ p2 = P2 + r * CW * (size_t)NPAD;
    const int* __restrict__ cc = CNT2 + r * CW;
    const int l0 = tid, l1 = tid + 512, l2 = tid + 1024, l3 = tid + 1536;
    const int c0 = min(cc[l0], NPAD), c1 = min(cc[l1], NPAD);
    const int c2 = min(cc[l2], NPAD), c3 = min(cc[l3], NPAD);
    float S0x = sbx[l0], S1x = sbx[l1], S2x = sbx[l2], S3x = sbx[l3];
    float S0y = sby[l0], S1y = sby[l1], S2y = sby[l2], S3y = sby[l3];
    const int cm = max(max(c0, c1), max(c2, c3));
    for (int p = 0; p < cm; ++p) {
        const int* rp = p2 + (size_t)p * CW;
        if (p < c0) { float2 v = u[rp[l0]]; S0x += v.x; S0y += v.y; }
        if (p < c1) { float2 v = u[rp[l1]]; S1x += v.x; S1y += v.y; }
        if (p < c2) { float2 v = u[rp[l2]]; S2x += v.x; S2y += v.y; }
        if (p < c3) { float2 v = u[rp[l3]]; S3x += v.x; S3y += v.y; }
    }
    float2* o = Pf2 + r * CW;
    o[l0] = make_float2(S0x, S0y); o[l1] = make_float2(S1x, S1y);
    o[l2] = make_float2(S2x, S2y); o[l3] = make_float2(S3x, S3y);
}

// ---- node kernels (shared) ----
__global__ void k_prep(const int* __restrict__ Pd, const float* __restrict__ x,
        float* __restrict__ dis, float* __restrict__ t, float* __restrict__ degf,
        int n, int C) {
    int c = blockIdx.x * blockDim.x + threadIdx.x;
    if (c >= n) return;
    int k = c >> CSH, l = c & (CW - 1);
    int d = 0;
    for (int j = 0; j < C; ++j) d += Pd[((size_t)k * C + j) * CW + l];
    degf[c] = (float)d;
    float di = rsqrtf(1.0f + (float)d);
    dis[c] = di;
    t[c] = di * x[c];
}

__global__ void k_mlp(const float* __restrict__ Pf, const float* __restrict__ dis,
        const float* __restrict__ t, const float* __restrict__ W1,
        const float* __restrict__ b1, const float* __restrict__ W2,
        float2* __restrict__ u, int n, int C) {
    int c = blockIdx.x * blockDim.x + threadIdx.x;
    if (c >= n) return;
    int k = c >> CSH, l = c & (CW - 1);
    float S = 0.0f;
    for (int j = 0; j < C; ++j) S += Pf[((size_t)k * C + j) * CW + l];
    float di = dis[c];
    float s = di * (S + t[c]);
    float a0 = 0.0f, a1 = 0.0f;
#pragma unroll
    for (int j = 0; j < 16; ++j) {
        float hh = fmaxf(fmaf(s, W1[j], b1[j]), 0.0f);
        a0 = fmaf(W2[j],      hh, a0);
        a1 = fmaf(W2[16 + j], hh, a1);
    }
    u[c] = make_float2(di * a0, di * a1);
}

__global__ void k_out2(const float2* __restrict__ Pf2, const float* __restrict__ dis,
        const float2* __restrict__ u, const float* __restrict__ b2,
        float2* __restrict__ out, int n, int C) {
    int c = blockIdx.x * blockDim.x + threadIdx.x;
    if (c >= n) return;
    int k = c >> CSH, l = c & (CW - 1);
    float sx = 0.0f, sy = 0.0f;
    for (int j = 0; j < C; ++j) {
        float2 p = Pf2[((size_t)k * C + j) * CW + l];
        sx += p.x; sy += p.y;
    }
    float di = dis[c];
    float2 uc = u[c];
    out[c] = make_float2(b2[0] + di * (sx + uc.x),
                         b2[1] + di * (sy + uc.y));
}

// ================= R13 kernels (secondary path, unchanged) =================
__global__ __launch_bounds__(512) void k_deg(const int* __restrict__ P1,
        const int* __restrict__ CNT, int* __restrict__ Pd, int NC, int C, int PAD) {
    __shared__ __align__(16) int bin[CW];
    const int k = blockIdx.x / C, j = blockIdx.x % C;
    const int tid = threadIdx.x, wave = tid >> 6, lane = tid & 63;
    for (int q = tid; q < CW; q += 512) bin[q] = 0;
    __syncthreads();
    const int b0 = (j * NB1) / C, b1 = ((j + 1) * NB1) / C;
    for (int b = b0 + wave; b < b1; b += 8) {
        const int cnt = CNT[b * NC + k];
        const int* seg = P1 + ((size_t)b * NC + k) * PAD;
        const int nv = cnt & ~3;
        for (int i = lane * 4; i < nv; i += 256) {
            int4 a = *reinterpret_cast<const int4*>(seg + i);
            atomicAdd(&bin[a.x & (CW - 1)], 1); atomicAdd(&bin[a.y & (CW - 1)], 1);
            atomicAdd(&bin[a.z & (CW - 1)], 1); atomicAdd(&bin[a.w & (CW - 1)], 1);
        }
        for (int i = nv + lane; i < cnt; i += 64)
            atomicAdd(&bin[seg[i] & (CW - 1)], 1);
    }
    __syncthreads();
    int4* o4 = reinterpret_cast<int4*>(Pd + ((size_t)k * C + j) * CW);
    const int4* b4 = reinterpret_cast<const int4*>(bin);
    for (int q = tid; q < CW / 4; q += 512) o4[q] = b4[q];
}

__global__ __launch_bounds__(512) void k_aggf(const int* __restrict__ P1,
        const int* __restrict__ CNT, const float* __restrict__ src,
        float* __restrict__ Pf, int NC, int C, int PAD) {
    __shared__ __align__(16) float bin[CW];
    const int k = blockIdx.x / C, j = blockIdx.x % C;
    const int tid = threadIdx.x, wave = tid >> 6, lane = tid & 63;
    for (int q = tid; q < CW; q += 512) bin[q] = 0.0f;
    __syncthreads();
    const int b0 = (j * NB1) / C, b1 = ((j + 1) * NB1) / C;
    for (int b = b0 + wave; b < b1; b += 8) {
        const int cnt = CNT[b * NC + k];
        const int* seg = P1 + ((size_t)b * NC + k) * PAD;
        const int nv = cnt & ~3;
        for (int i = lane * 4; i < nv; i += 256) {
            int4 a = *reinterpret_cast<const int4*>(seg + i);
            float v0 = src[a.x >> CSH], v1 = src[a.y >> CSH];
            float v2 = src[a.z >> CSH], v3 = src[a.w >> CSH];
            atomicAdd(&bin[a.x & (CW - 1)], v0); atomicAdd(&bin[a.y & (CW - 1)], v1);
            atomicAdd(&bin[a.z & (CW - 1)], v2); atomicAdd(&bin[a.w & (CW - 1)], v3);
        }
        for (int i = nv + lane; i < cnt; i += 64) {
            int p = seg[i];
            atomicAdd(&bin[p & (CW - 1)], src[p >> CSH]);
        }
    }
    __syncthreads();
    float4* o4 = reinterpret_cast<float4*>(Pf + ((size_t)k * C + j) * CW);
    const float4* b4 = reinterpret_cast<const float4*>(bin);
    for (int q = tid; q < CW / 4; q += 512) o4[q] = b4[q];
}

__device__ __forceinline__ unsigned long long pack_u(float2 uv) {
    float cx = fminf(fmaxf(uv.x, -15.9f), 15.9f);
    float cy = fminf(fmaxf(uv.y, -15.9f), 15.9f);
    unsigned int tx = (unsigned int)__float2int_rn(fmaf(cx, 524288.0f, 8388608.0f));
    unsigned int ty = (unsigned int)__float2int_rn(fmaf(cy, 524288.0f, 8388608.0f));
    return ((unsigned long long)ty << 32) | tx;
}

__global__ __launch_bounds__(512) void k_agg2f(const int* __restrict__ P1,
        const int* __restrict__ CNT, const float2* __restrict__ u,
        unsigned long long* __restrict__ Pq, int NC, int C, int PAD) {
    __shared__ unsigned long long bin[CW];   // 16 KB
    const int k = blockIdx.x / C, j = blockIdx.x % C;
    const int tid = threadIdx.x, wave = tid >> 6, lane = tid & 63;
    for (int q = tid; q < CW; q += 512) bin[q] = 0ull;
    __syncthreads();
    const int b0 = (j * NB1) / C, b1 = ((j + 1) * NB1) / C;
    for (int b = b0 + wave; b < b1; b += 8) {
        const int cnt = CNT[b * NC + k];
        const int* seg = P1 + ((size_t)b * NC + k) * PAD;
        const int nv = cnt & ~3;
        for (int i = lane * 4; i < nv; i += 256) {
            int4 a = *reinterpret_cast<const int4*>(seg + i);
            unsigned long long q0 = pack_u(u[a.x >> CSH]);
            unsigned long long q1 = pack_u(u[a.y >> CSH]);
            unsigned long long q2 = pack_u(u[a.z >> CSH]);
            unsigned long long q3 = pack_u(u[a.w >> CSH]);
            atomicAdd(&bin[a.x & (CW - 1)], q0); atomicAdd(&bin[a.y & (CW - 1)], q1);
            atomicAdd(&bin[a.z & (CW - 1)], q2); atomicAdd(&bin[a.w & (CW - 1)], q3);
        }
        for (int i = nv + lane; i < cnt; i += 64) {
            int p = seg[i];
            atomicAdd(&bin[p & (CW - 1)], pack_u(u[p >> CSH]));
        }
    }
    __syncthreads();
    unsigned long long* o = Pq + ((size_t)k * C + j) * CW;
    for (int q = tid; q < CW; q += 512) o[q] = bin[q];
}

__global__ void k_out(const unsigned long long* __restrict__ Pq,
        const float* __restrict__ dis, const float* __restrict__ degf,
        const float2* __restrict__ u, const float* __restrict__ b2,
        float2* __restrict__ out, int n, int C) {
    int c = blockIdx.x * blockDim.x + threadIdx.x;
    if (c >= n) return;
    int k = c >> CSH, l = c & (CW - 1);
    unsigned long long S = 0ull;
    for (int j = 0; j < C; ++j) S += Pq[((size_t)k * C + j) * CW + l];
    double dg = (double)degf[c] * 8388608.0;
    double sx = ((double)(unsigned int)(S & 0xffffffffULL) - dg) * (1.0 / 524288.0);
    double sy = ((double)(unsigned int)(S >> 32)            - dg) * (1.0 / 524288.0);
    float di = dis[c];
    float2 uc = u[c];
    out[c] = make_float2(b2[0] + di * ((float)sx + uc.x),
                         b2[1] + di * ((float)sy + uc.y));
}

// ---------- generic atomic fallback (any n/e, slow but correct) ----------
__global__ void f_init_deg(float* deg, int n) {
    int i = blockIdx.x * blockDim.x + threadIdx.x;
    if (i < n) deg[i] = 1.0f;
}
__global__ void f_deg(const int* col, float* deg, int e) {
    int i = blockIdx.x * blockDim.x + threadIdx.x;
    if (i < e) atomicAdd(&deg[col[i]], 1.0f);
}
__global__ void f_dis_self(const float* x, float* deg_dis, float* s, int n) {
    int i = blockIdx.x * blockDim.x + threadIdx.x;
    if (i < n) { float di = rsqrtf(deg_dis[i]); deg_dis[i] = di; s[i] = di * di * x[i]; }
}
__global__ void f_agg1(const int* row, const int* col, const float* dis,
                       const float* x, float* s, int e) {
    int i = blockIdx.x * blockDim.x + threadIdx.x;
    if (i < e) { int r = row[i], c = col[i]; atomicAdd(&s[c], dis[r] * dis[c] * x[r]); }
}
__global__ void f_mlp(const float* s, const float* dis, const float* W1,
                      const float* b1, const float* W2, const float* b2,
                      float* h2, float* out, int n) {
    int i = blockIdx.x * blockDim.x + threadIdx.x;
    if (i < n) {
        float sv = s[i], a0 = 0.0f, a1 = 0.0f;
#pragma unroll
        for (int j = 0; j < 16; ++j) {
            float h1 = fmaxf(sv * W1[j] + b1[j], 0.0f);
            a0 = fmaf(W2[j], h1, a0); a1 = fmaf(W2[16 + j], h1, a1);
        }
        h2[2 * i] = a0; h2[2 * i + 1] = a1;
        float d2 = dis[i] * dis[i];
        out[2 * i] = b2[0] + d2 * a0; out[2 * i + 1] = b2[1] + d2 * a1;
    }
}
__global__ void f_agg2(const int* row, const int* col, const float* dis,
                       const float* h2, float* out, int e) {
    int i = blockIdx.x * blockDim.x + threadIdx.x;
    if (i < e) {
        int r = row[i], c = col[i];
        float nm = dis[r] * dis[c];
        float2 hv = *reinterpret_cast<const float2*>(&h2[2 * r]);
        atomicAdd(&out[2 * c], nm * hv.x);
        atomicAdd(&out[2 * c + 1], nm * hv.y);
    }
}
// -------------------------------------------------------------------------

extern "C" void kernel_launch(void* const* d_in, const int* in_sizes, int n_in,
                              void* d_out, int out_size, void* d_ws, size_t ws_size,
                              hipStream_t stream) {
    const float* x  = (const float*)d_in[0];
    const int*   ei = (const int*)d_in[1];
    const float* W1 = (const float*)d_in[2];
    const float* b1 = (const float*)d_in[3];
    const float* W2 = (const float*)d_in[4];
    const float* b2 = (const float*)d_in[5];

    const int n = in_sizes[0];
    const int e = in_sizes[1] / 2;
    const int* row = ei;
    const int* col = ei + e;

    const int NC = (n + CW - 1) >> CSH;
    const size_t NCW = (size_t)NC * CW;
    const size_t ws4 = ws_size / 4;

    // scatter sizing (shared by R14/R13)
    const int chunk = chunk_of(e);
    const int lam = NC > 0 ? chunk / NC : 0;
    int PAD = lam + 8 * (int)std::sqrt((double)(lam > 0 ? lam : 1)) + 32;
    PAD = (PAD + 3) & ~3;
    const size_t p1sz = (size_t)NB1 * NC * PAD;
    const int gn = (n + 255) / 256;

    // ---------------- R14 path: 2 atomic passes + free gathers ----------------
    if (NC <= MAXNC && NC >= 4 && e > 0) {
        const int C2 = 10;                  // 49*10=490 blocks -> ~2/CU balanced
        const size_t cells = (size_t)NC * C2 * CW;
        const double lm = (double)e / (double)cells;
        if (lm <= 32.0) {   // keeps spill capacity math safe
            const int na = (n + 3) & ~3;
            const size_t fixed4 = p1sz + (size_t)NB1 * NC + 5ull * (size_t)na;
            // NPAD rungs: lambda + k*sqrt(lambda) + slack (largest that fits)
            int cand[3];
            cand[0] = (int)std::ceil(lm + 2.5 * std::sqrt(lm) + 6.0);
            cand[1] = (int)std::ceil(lm + 1.2 * std::sqrt(lm) + 2.0);
            cand[2] = (int)std::ceil(lm + 0.5 * std::sqrt(lm));
            for (int ci = 0; ci < 3; ++ci) {
                const int NPAD = cand[ci] > 4 ? cand[ci] : 4;
                const size_t need = fixed4
                                  + cells                         // CNT2
                                  + (size_t)NC * C2 + 64          // SPC (+ slack)
                                  + (size_t)NC * C2 * SPAD        // SP
                                  + cells * (size_t)NPAD;         // P2
                if (need > ws4 || p1sz < cells * 3) continue;     // Pf+Pf2 alias in P1

                int*    P1   = (int*)d_ws;
                int*    CNT  = P1 + p1sz;
                float*  dis  = (float*)(CNT + (size_t)NB1 * NC);
                float*  t    = dis + na;
                float*  degf = t + na;
                float2* u    = (float2*)(degf + na);
                int*    CNT2 = (int*)d_ws + fixed4;
                int*    SPC  = CNT2 + cells;
                int*    SP   = SPC + (size_t)NC * C2 + 64;
                int*    P2   = SP + (size_t)NC * C2 * SPAD;
                float*  Pf   = (float*)P1;                 // P1 dead after place
                float2* Pf2  = (float2*)(P1 + cells);

                k_scatter<<<NB1, 256, 0, stream>>>(row, col, P1, CNT, e, NC, PAD);
                k_place  <<<NC * C2, 512, 0, stream>>>(P1, CNT, P2, CNT2, SP, SPC,
                                                       NC, C2, PAD, NPAD);
                k_prep   <<<gn, 256, 0, stream>>>(CNT2, x, dis, t, degf, n, C2);
                k_gath1  <<<NC * C2, 512, 0, stream>>>(P2, CNT2, SP, SPC, t, Pf, NPAD);
                k_mlp    <<<gn, 256, 0, stream>>>(Pf, dis, t, W1, b1, W2, u, n, C2);
                k_gath2  <<<NC * C2, 512, 0, stream>>>(P2, CNT2, SP, SPC, u, Pf2, NPAD);
                k_out2   <<<gn, 256, 0, stream>>>(Pf2, dis, u, b2,
                                                  (float2*)d_out, n, C2);
                return;
            }
        }
    }

    // ---------------- R13 path (previous best) ----------------
    size_t base4 = p1sz + (size_t)NB1 * NC + 5ull * (size_t)n;
    base4 = (base4 + 3) & ~(size_t)3;
    long long avail = (long long)ws4 - (long long)base4;
    int Cs = (avail > 0) ? (int)min((long long)32, avail / (long long)NCW) : 0;
    int Cv = (avail > 0) ? (int)min((long long)24, avail / (long long)(2 * NCW)) : 0;

    if (NC > MAXNC || NC < 4 || Cs < 2 || Cv < 2 ||
        (long long)e > 100ll * (long long)n) {
        float* dis = (float*)d_ws; float* s = dis + n; float* h2 = s + n;
        const int ge = (e + 255) / 256;
        f_init_deg<<<gn, 256, 0, stream>>>(dis, n);
        f_deg<<<ge, 256, 0, stream>>>(col, dis, e);
        f_dis_self<<<gn, 256, 0, stream>>>(x, dis, s, n);
        f_agg1<<<ge, 256, 0, stream>>>(row, col, dis, x, s, e);
        f_mlp<<<gn, 256, 0, stream>>>(s, dis, W1, b1, W2, b2, h2, (float*)d_out, n);
        f_agg2<<<ge, 256, 0, stream>>>(row, col, dis, h2, (float*)d_out, e);
        return;
    }

    int*    P1   = (int*)d_ws;
    int*    CNT  = P1 + p1sz;
    float*  dis  = (float*)(CNT + (size_t)NB1 * NC);
    float*  t    = dis + n;
    float*  degf = t + n;
    float2* u    = (float2*)(degf + n);
    float*  Pp   = (float*)((char*)d_ws + base4 * 4);

    k_scatter<<<NB1, 256, 0, stream>>>(row, col, P1, CNT, e, NC, PAD);
    k_deg    <<<NC * Cs, 512, 0, stream>>>(P1, CNT, (int*)Pp, NC, Cs, PAD);
    k_prep   <<<gn, 256, 0, stream>>>((const int*)Pp, x, dis, t, degf, n, Cs);
    k_aggf   <<<NC * Cs, 512, 0, stream>>>(P1, CNT, t, Pp, NC, Cs, PAD);
    k_mlp    <<<gn, 256, 0, stream>>>(Pp, dis, t, W1, b1, W2, u, n, Cs);
    k_agg2f  <<<NC * Cv, 512, 0, stream>>>(P1, CNT, u, (unsigned long long*)Pp, NC, Cv, PAD);
    k_out    <<<gn, 256, 0, stream>>>((const unsigned long long*)Pp, dis, degf, u, b2,
                                      (float2*)d_out, n, Cv);
}